// Round 11
// baseline (320.040 us; speedup 1.0000x reference)
//
#include <hip/hip_runtime.h>
#include <hip/hip_bf16.h>
#include <math.h>

#define NN 50000     // nodes
#define NE 400000    // edges
#define HH 4         // heads
#define CC 64        // per-head dim
#define HC 256       // H*C
#define GG 64        // graphs
#define NB 196       // scan blocks: ceil(NN/256)
#define ENCB 12500   // encoder blocks
#define WCB 640      // wconv blocks
#define GATB 12500   // gat blocks (4 nodes each)

typedef short v8s __attribute__((ext_vector_type(8)));
typedef float f32x4 __attribute__((ext_vector_type(4)));

static __device__ inline unsigned short f2bf(float v) {
  __hip_bfloat16 b = __float2bfloat16(v);
  return *reinterpret_cast<unsigned short*>(&b);
}
// packed bf16 pair -> f32 (bf16 value = bit pattern << 16)
static __device__ inline float bflo(unsigned u) { return __uint_as_float(u << 16); }
static __device__ inline float bfhi(unsigned u) { return __uint_as_float(u & 0xffff0000u); }

// width-16 xor-butterfly step via ds_swizzle BitMode: ONE DS instr, no VALU
// addr math. offset = (xor<<10)|0x1F.
static __device__ inline float swz_xor(float v, int imm) {
  switch (imm) {
    case 8: return __int_as_float(__builtin_amdgcn_ds_swizzle(__float_as_int(v), 0x201F));
    case 4: return __int_as_float(__builtin_amdgcn_ds_swizzle(__float_as_int(v), 0x101F));
    case 2: return __int_as_float(__builtin_amdgcn_ds_swizzle(__float_as_int(v), 0x081F));
    default: return __int_as_float(__builtin_amdgcn_ds_swizzle(__float_as_int(v), 0x041F));
  }
}

// async global->LDS, 16B per lane. LDS dest is wave-uniform base + lane*16.
static __device__ inline void gload_lds16(const void* g, void* l) {
  __builtin_amdgcn_global_load_lds(
      (const __attribute__((address_space(1))) void*)g,
      (__attribute__((address_space(3))) void*)l, 16, 0, 0);
}

// ---- head kernel: encoder + all 4 W preps + setup, region-dispatched ----
// bid <  ENCB               : encoder  h0 = relu(x @ enc_w + enc_b) -> bf16
// bid <  ENCB+WCB           : wconv    W[K,256] f32 -> Wt bf16 [256][K]
// bid <  ENCB+WCB+NB        : setup    zero deg, zero pool, seg bounds
__global__ __launch_bounds__(256) void head_kernel(
    const float* __restrict__ x, const float* __restrict__ enc_w,
    const float* __restrict__ enc_b, unsigned short* __restrict__ h0,
    const float* __restrict__ g1_wl, const float* __restrict__ g1_wr,
    const float* __restrict__ g2_wl, const float* __restrict__ g2_wr,
    unsigned short* __restrict__ wt1, unsigned short* __restrict__ wt2,
    const int* __restrict__ batch, int* __restrict__ deg,
    float* __restrict__ pool, int* __restrict__ bounds) {
  int bid = blockIdx.x, tid = threadIdx.x;
  if (bid < ENCB) {
    int idx = bid * 256 + tid;
    int node = idx >> 6, col = idx & 63;
    const float* xr = x + node * 8;
    float acc = enc_b[col];
#pragma unroll
    for (int k = 0; k < 8; ++k) acc += xr[k] * enc_w[k * 64 + col];
    h0[idx] = f2bf(fmaxf(acc, 0.f));
  } else if (bid < ENCB + WCB) {
    int idx = (bid - ENCB) * 256 + tid;
    const float* W; unsigned short* Wt; int K; int base;
    if (idx < 16384)        { W = g1_wl; Wt = wt1;                     K = 64;  base = idx; }
    else if (idx < 32768)   { W = g1_wr; Wt = wt1 + (size_t)256 * 64;  K = 64;  base = idx - 16384; }
    else if (idx < 98304)   { W = g2_wl; Wt = wt2;                     K = 256; base = idx - 32768; }
    else if (idx < 163840)  { W = g2_wr; Wt = wt2 + (size_t)256 * 256; K = 256; base = idx - 98304; }
    else return;
    int k = base >> 8, n = base & 255;
    Wt[n * K + k] = f2bf(W[base]);
  } else {
    int sb = bid - ENCB - WCB;           // 0..NB-1
    int i = sb * 256 + tid;
    if (i < NN) deg[i] = 0;
    if (sb < GG) pool[sb * 256 + tid] = 0.f;
    if (sb == NB - 1 && tid <= GG) {
      int g = tid, lo = 0, hi = NN;
      while (lo < hi) {
        int mid = (lo + hi) >> 1;
        if (batch[mid] < g) lo = mid + 1; else hi = mid;
      }
      bounds[g] = lo;
    }
  }
}

// ------- MFMA matmul: {xl,xr}(bf16)[M,256] = A(bf16) @ [Wl;Wr] (bias on xl) -------
// 2-phase double-buffered pipeline (T3-minimum), global_load_lds w16, swizzled.
template <int K>
__global__ __launch_bounds__(256) void matmul_mfma_kernel(
    const unsigned short* __restrict__ A, const unsigned short* __restrict__ Wt,
    const float* __restrict__ bias,
    unsigned short* __restrict__ outL, unsigned short* __restrict__ outR, int M) {
  const int mmb = ((M + 127) >> 7) << 2;
  int bid = blockIdx.x;
  {
    int q = mmb >> 3, r = mmb & 7;
    int xcd = bid & 7, off2 = bid >> 3;
    bid = (xcd < r ? xcd * (q + 1) : r * (q + 1) + (xcd - r) * q) + off2;
  }
  __shared__ __attribute__((aligned(16))) unsigned short lds[16384];
  const int tid = threadIdx.x;
  const int wave = tid >> 6;
  const int lane = tid & 63;
  const int quad = lane >> 4;
  const int lrow = lane & 15;
  const int wr = (wave & 1) * 64;
  const int wc = (wave >> 1) * 64;
  const int r0 = (bid >> 2) * 128;
  const int n0 = (bid & 3) * 128;

  f32x4 acc[4][4];
#pragma unroll
  for (int i = 0; i < 4; ++i)
#pragma unroll
    for (int j = 0; j < 4; ++j) acc[i][j] = (f32x4){0.f, 0.f, 0.f, 0.f};

  const int lrA0 = (wave * 2) * 16 + (lane >> 2);
  const int lrA1 = lrA0 + 16;
  const int c    = lane & 3;
  const int cs0  = c ^ ((lrA0 >> 1) & 3);
  const int cs1  = c ^ ((lrA1 >> 1) & 3);
  int ga0 = r0 + lrA0; if (ga0 >= M) ga0 = M - 1;
  int ga1 = r0 + lrA1; if (ga1 >= M) ga1 = M - 1;
  const unsigned short* srcA0 = A  + (size_t)ga0 * K + cs0 * 8;
  const unsigned short* srcA1 = A  + (size_t)ga1 * K + cs1 * 8;
  const unsigned short* srcB0 = Wt + (size_t)(n0 + lrA0) * K + cs0 * 8;
  const unsigned short* srcB1 = Wt + (size_t)(n0 + lrA1) * K + cs1 * 8;
  const int doff0 = (wave * 2 + 0) * 512;
  const int doff1 = (wave * 2 + 1) * 512;
  const int qsw = (quad ^ ((lrow >> 1) & 3)) * 8;

  constexpr int NT = K / 32;
  gload_lds16(srcA0, &lds[doff0]);
  gload_lds16(srcA1, &lds[doff1]);
  gload_lds16(srcB0, &lds[4096 + doff0]);
  gload_lds16(srcB1, &lds[4096 + doff1]);
  __syncthreads();

  int cur = 0;
#pragma unroll
  for (int t = 0; t < NT; ++t) {
    if (t + 1 < NT) {
      const int k0 = (t + 1) * 32;
      const int nb = (cur ^ 1) * 8192;
      gload_lds16(srcA0 + k0, &lds[nb + doff0]);
      gload_lds16(srcA1 + k0, &lds[nb + doff1]);
      gload_lds16(srcB0 + k0, &lds[nb + 4096 + doff0]);
      gload_lds16(srcB1 + k0, &lds[nb + 4096 + doff1]);
    }
    const unsigned short* base = &lds[cur * 8192];
    v8s af[4], bf[4];
#pragma unroll
    for (int rt = 0; rt < 4; ++rt)
      af[rt] = *(const v8s*)&base[(wr + rt * 16 + lrow) * 32 + qsw];
#pragma unroll
    for (int ct = 0; ct < 4; ++ct)
      bf[ct] = *(const v8s*)&base[4096 + (wc + ct * 16 + lrow) * 32 + qsw];
#pragma unroll
    for (int rt = 0; rt < 4; ++rt)
#pragma unroll
      for (int ct = 0; ct < 4; ++ct)
        acc[rt][ct] = __builtin_amdgcn_mfma_f32_16x16x32_bf16(af[rt], bf[ct], acc[rt][ct], 0, 0, 0);
    __syncthreads();
    cur ^= 1;
  }

  const bool isL = (n0 < 256);
  unsigned short* outp = isL ? outL : outR;
  const int cbase = isL ? n0 : (n0 - 256);
  constexpr int SP = 136;
  unsigned short* stage = lds;

#pragma unroll
  for (int rt = 0; rt < 4; ++rt) {
    __syncthreads();
#pragma unroll
    for (int ct = 0; ct < 4; ++ct) {
      int col = wc + ct * 16 + lrow;
      float b = isL ? bias[cbase + col] : 0.f;
#pragma unroll
      for (int r = 0; r < 4; ++r) {
        int sr = (wave & 1) * 16 + quad * 4 + r;
        stage[sr * SP + col] = f2bf(acc[rt][ct][r] + b);
      }
    }
    __syncthreads();
    int sr = tid >> 3;
    int c0 = (tid & 7) * 16;
    int grow = r0 + (sr >> 4) * 64 + rt * 16 + (sr & 15);
    if (grow < M) {
      uint4 v0 = *(const uint4*)&stage[sr * SP + c0];
      uint4 v1 = *(const uint4*)&stage[sr * SP + c0 + 8];
      *(uint4*)&outp[(size_t)grow * 256 + cbase + c0] = v0;
      *(uint4*)&outp[(size_t)grow * 256 + cbase + c0 + 8] = v1;
    }
  }
}

// ---------------- CSR build ----------------
__global__ void degree_kernel(const int* __restrict__ ei, int* __restrict__ deg) {
  int e = blockIdx.x * 256 + threadIdx.x;
  if (e < NE) atomicAdd(&deg[ei[NE + e]], 1);
}

__global__ __launch_bounds__(256) void blocksum_kernel(
    const int* __restrict__ deg, int* __restrict__ bsum) {
  int t = threadIdx.x;
  int i = blockIdx.x * 256 + t;
  int v = (i < NN) ? deg[i] : 0;
#pragma unroll
  for (int off = 32; off; off >>= 1) v += __shfl_down(v, off, 64);
  __shared__ int ws[4];
  if ((t & 63) == 0) ws[t >> 6] = v;
  __syncthreads();
  if (t == 0) bsum[blockIdx.x] = ws[0] + ws[1] + ws[2] + ws[3];
}

// rowstart with INLINE block-prefix: each block reduces bsum[0..b) itself
// (196 coalesced ints + wave reduce) -- deletes the serial single-block
// blockscan launch. No cross-block waits.
__global__ __launch_bounds__(256) void rowstart_kernel(
    const int* __restrict__ deg, const int* __restrict__ bsum,
    int* __restrict__ rowstart, int* __restrict__ cursor) {
  __shared__ int s[256];
  __shared__ int ws[4];
  __shared__ int wt[4];
  int t = threadIdx.x;
  int b = blockIdx.x;
  int bv = (t < NB) ? bsum[t] : 0;
  int cpre = (t < b) ? bv : 0;
#pragma unroll
  for (int off = 32; off; off >>= 1) cpre += __shfl_down(cpre, off, 64);
  if ((t & 63) == 0) ws[t >> 6] = cpre;
  int tot = bv;
#pragma unroll
  for (int off = 32; off; off >>= 1) tot += __shfl_down(tot, off, 64);
  if ((t & 63) == 0) wt[t >> 6] = tot;
  __syncthreads();
  int pre = ws[0] + ws[1] + ws[2] + ws[3];
  int i = b * 256 + t;
  int v = (i < NN) ? deg[i] : 0;
  s[t] = v;
  __syncthreads();
  for (int off = 1; off < 256; off <<= 1) {
    int x = s[t];
    int y = (t >= off) ? s[t - off] : 0;
    __syncthreads();
    s[t] = x + y;
    __syncthreads();
  }
  if (i < NN) {
    int rs = pre + s[t] - v;
    rowstart[i] = rs;
    cursor[i] = rs;
  }
  if (b == NB - 1 && t == 0)
    rowstart[NN] = wt[0] + wt[1] + wt[2] + wt[3];
}

// CSR fill: int2 (src BYTE OFFSET = src*512, ea-bits) -> one aligned 8B store.
__global__ void fill_kernel(const int* __restrict__ ei, const float* __restrict__ ea,
                            int* __restrict__ cursor, int2* __restrict__ edges) {
  int e = blockIdx.x * 256 + threadIdx.x;
  if (e < NE) {
    int d = ei[NE + e];
    int pos = atomicAdd(&cursor[d], 1);
    edges[pos] = make_int2(ei[e] << 9, __float_as_int(ea[e]));
  }
}

// ---------------- fused GATv2 edge phase: wave per dst node ----
// Steady state: 2-stage named pipeline (A/B groups of 4, refill-in-place) --
// zero register-rotation moves (old e=f/p=q rotation was ~16 v_mov per 4
// edges, ~8-11% of per-edge VALU). Per-edge FP order unchanged (ascending i).
// POOL=true (layer 2): LDS-stage output, last-arriving wave emits ONE plain
// 1KB store to partial[blockIdx]; straddlers (~63/12500) use atomics to pool.
template <bool POOL>
__global__ __launch_bounds__(256) void gat_fused_kernel(
    const int* __restrict__ rowstart, const int2* __restrict__ edges,
    const unsigned short* __restrict__ xl, const unsigned short* __restrict__ xr,
    const float* __restrict__ we, const float* __restrict__ att,
    const float* __restrict__ bias, unsigned short* __restrict__ outb,
    const int* __restrict__ batch, float* __restrict__ pool,
    float* __restrict__ partial) {
  __shared__ float pacc[POOL ? 4 : 1][POOL ? 256 : 1];
  __shared__ int pb[4];
  __shared__ int done;
  int tid = threadIdx.x;
  int node = (blockIdx.x * 256 + tid) >> 6;
  int lane = tid & 63;
  int wave = tid >> 6;
  if constexpr (POOL) {
    if (tid == 0) done = 0;
    if (lane == 0) pb[wave] = batch[node];
    __syncthreads();                     // uniform start point: ~free; orders done=0
  }
  int r0 = __builtin_amdgcn_readfirstlane(rowstart[node]);
  int r1 = __builtin_amdgcn_readfirstlane(rowstart[node + 1]);
  const char* xlb = (const char*)xl;          // UNIFORM gather base
  const unsigned lane8 = (unsigned)lane * 8u;
  uint2 rp = ((const uint2*)xr)[(size_t)node * 64 + lane];
  float4 r = make_float4(bflo(rp.x), bfhi(rp.x), bflo(rp.y), bfhi(rp.y));
  float4 wv = ((const float4*)we)[lane];
  float4 at = ((const float4*)att)[lane];
  const float LOG2E = 1.442695040888963f;
  at.x *= LOG2E; at.y *= LOG2E; at.z *= LOG2E; at.w *= LOG2E;
  float4 acc = make_float4(0.f, 0.f, 0.f, 0.f);
  float denom = 0.f;

  auto edge_step = [&](float eav, uint2 p) {
    float4 a = make_float4(bflo(p.x), bfhi(p.x), bflo(p.y), bfhi(p.y));
    float s0 = a.x + (r.x + eav * wv.x);
    float s1 = a.y + (r.y + eav * wv.y);
    float s2 = a.z + (r.z + eav * wv.z);
    float s3 = a.w + (r.w + eav * wv.w);
    s0 = fmaxf(s0, 0.2f * s0);
    s1 = fmaxf(s1, 0.2f * s1);
    s2 = fmaxf(s2, 0.2f * s2);
    s3 = fmaxf(s3, 0.2f * s3);
    float p4 = (s0 * at.x + s1 * at.y) + (s2 * at.z + s3 * at.w);
    p4 += swz_xor(p4, 8);
    p4 += swz_xor(p4, 4);
    p4 += swz_xor(p4, 2);
    p4 += swz_xor(p4, 1);
    float ex = exp2f(p4);
    denom += ex;
    acc.x += ex * a.x; acc.y += ex * a.y; acc.z += ex * a.z; acc.w += ex * a.w;
  };
  auto gath = [&](int byteoff) {
    return *(const uint2*)(xlb + (unsigned)byteoff + lane8);
  };

  int i = r0;
  if (i + 8 <= r1) {                     // 2-stage pipeline, no rotation moves
    int2 eA0 = edges[i];     int2 eA1 = edges[i + 1];
    int2 eA2 = edges[i + 2]; int2 eA3 = edges[i + 3];
    uint2 pA0 = gath(eA0.x), pA1 = gath(eA1.x), pA2 = gath(eA2.x), pA3 = gath(eA3.x);
    int2 eB0 = edges[i + 4]; int2 eB1 = edges[i + 5];
    int2 eB2 = edges[i + 6]; int2 eB3 = edges[i + 7];
    uint2 pB0 = gath(eB0.x), pB1 = gath(eB1.x), pB2 = gath(eB2.x), pB3 = gath(eB3.x);
    for (; i + 16 <= r1; i += 8) {
      edge_step(__int_as_float(eA0.y), pA0);
      edge_step(__int_as_float(eA1.y), pA1);
      edge_step(__int_as_float(eA2.y), pA2);
      edge_step(__int_as_float(eA3.y), pA3);
      eA0 = edges[i + 8];  eA1 = edges[i + 9];
      eA2 = edges[i + 10]; eA3 = edges[i + 11];
      pA0 = gath(eA0.x); pA1 = gath(eA1.x); pA2 = gath(eA2.x); pA3 = gath(eA3.x);
      edge_step(__int_as_float(eB0.y), pB0);
      edge_step(__int_as_float(eB1.y), pB1);
      edge_step(__int_as_float(eB2.y), pB2);
      edge_step(__int_as_float(eB3.y), pB3);
      eB0 = edges[i + 12]; eB1 = edges[i + 13];
      eB2 = edges[i + 14]; eB3 = edges[i + 15];
      pB0 = gath(eB0.x); pB1 = gath(eB1.x); pB2 = gath(eB2.x); pB3 = gath(eB3.x);
    }
    edge_step(__int_as_float(eA0.y), pA0);   // drain A then B (ascending i)
    edge_step(__int_as_float(eA1.y), pA1);
    edge_step(__int_as_float(eA2.y), pA2);
    edge_step(__int_as_float(eA3.y), pA3);
    edge_step(__int_as_float(eB0.y), pB0);
    edge_step(__int_as_float(eB1.y), pB1);
    edge_step(__int_as_float(eB2.y), pB2);
    edge_step(__int_as_float(eB3.y), pB3);
    i += 8;
  } else if (i + 4 <= r1) {
    int2 e0 = edges[i];     int2 e1 = edges[i + 1];
    int2 e2 = edges[i + 2]; int2 e3 = edges[i + 3];
    uint2 p0 = gath(e0.x), p1 = gath(e1.x), p2 = gath(e2.x), p3 = gath(e3.x);
    edge_step(__int_as_float(e0.y), p0);
    edge_step(__int_as_float(e1.y), p1);
    edge_step(__int_as_float(e2.y), p2);
    edge_step(__int_as_float(e3.y), p3);
    i += 4;
  }
  for (; i < r1; ++i) {
    int2 e = edges[i];
    edge_step(__int_as_float(e.y), gath(e.x));
  }

  float inv = 1.f / (denom + 1e-16f);
  float4 bv = ((const float4*)bias)[lane];
  float4 o;
  o.x = fmaxf(acc.x * inv + bv.x, 0.f);
  o.y = fmaxf(acc.y * inv + bv.y, 0.f);
  o.z = fmaxf(acc.z * inv + bv.z, 0.f);
  o.w = fmaxf(acc.w * inv + bv.w, 0.f);
  uint2 pk;
  pk.x = (unsigned)f2bf(o.x) | ((unsigned)f2bf(o.y) << 16);
  pk.y = (unsigned)f2bf(o.z) | ((unsigned)f2bf(o.w) << 16);
  if constexpr (!POOL) {
    ((uint2*)outb)[(size_t)node * 64 + lane] = pk;
  } else {
    // bf16-rounded f32 values (bitwise = pool_kernel's summands)
    *(float4*)&pacc[wave][lane * 4] =
        make_float4(bflo(pk.x), bfhi(pk.x), bflo(pk.y), bfhi(pk.y));
    __threadfence_block();               // drain ds_writes before the bump
    int prev = 0;
    if (lane == 0) prev = atomicAdd(&done, 1);
    prev = __shfl(prev, 0, 64);
    if (prev == 3) {                     // last wave flushes; others exit now
      int b0 = pb[0], b1 = pb[1], b2 = pb[2], b3 = pb[3];
      float* pp = partial + (size_t)blockIdx.x * 256;
      if (b0 == b3 && b0 == b1 && b1 == b2) {   // sorted batch: common case
#pragma unroll
        for (int k = 0; k < 4; ++k) {
          int ch = lane + 64 * k;        // coalesced channel walk
          float s = (pacc[0][ch] + pacc[1][ch]) + (pacc[2][ch] + pacc[3][ch]);
          pp[ch] = s;                    // plain store, no atomic
        }
      } else {                           // straddler: zero partial + atomics
#pragma unroll
        for (int k = 0; k < 4; ++k) {
          int ch = lane + 64 * k;
          pp[ch] = 0.f;
          atomicAdd(&pool[b0 * 256 + ch], pacc[0][ch]);
          atomicAdd(&pool[b1 * 256 + ch], pacc[1][ch]);
          atomicAdd(&pool[b2 * 256 + ch], pacc[2][ch]);
          atomicAdd(&pool[b3 * 256 + ch], pacc[3][ch]);
        }
      }
    }
  }
}

// ---------------- partial -> pool reduction: graph x 8 segments ----------------
// 512 blocks x 256 thr (thread = channel): each block sums ~25 partial rows
// (coalesced 1KB reads) and issues ONE atomicAdd per channel.
__global__ __launch_bounds__(256) void reduce_kernel(
    const float* __restrict__ partial, const int* __restrict__ bounds,
    float* __restrict__ pool) {
  int g = blockIdx.x >> 3;
  int seg = blockIdx.x & 7;
  int ch = threadIdx.x;
  int lo = bounds[g], hi = bounds[g + 1];
  int pb0 = lo >> 2, pb1 = (hi + 3) >> 2;
  int per = (pb1 - pb0 + 7) >> 3;
  int s0 = pb0 + seg * per;
  int s1 = s0 + per; if (s1 > pb1) s1 = pb1;
  float s = 0.f;
#pragma unroll 4
  for (int p = s0; p < s1; ++p) s += partial[(size_t)p * 256 + ch];
  if (s0 < s1) atomicAdd(&pool[g * 256 + ch], s);
}

// ---------------- final MLP: one block (128 thr) per graph ----------------
__global__ __launch_bounds__(128) void mlp_kernel(
    const float* __restrict__ pool, const int* __restrict__ bounds,
    const float* __restrict__ p1w, const float* __restrict__ p1b,
    const float* __restrict__ lng, const float* __restrict__ lnb,
    const float* __restrict__ p2w, const float* __restrict__ p2b,
    const float* __restrict__ hw, const float* __restrict__ hb,
    float* __restrict__ out) {
  __shared__ float sg[256];
  __shared__ float red[128];
  __shared__ float sz[128];
  __shared__ float s2[64];
  int b = blockIdx.x, tid = threadIdx.x;
  float cntf = (float)(bounds[b + 1] - bounds[b]);
  float invc = 1.f / fmaxf(cntf, 1.f);
  for (int i = tid; i < 256; i += 128) sg[i] = pool[b * 256 + i] * invc;
  __syncthreads();
  float z = p1b[tid];
  for (int k = 0; k < 256; ++k) z += sg[k] * p1w[k * 128 + tid];
  red[tid] = z; __syncthreads();
  for (int off = 64; off; off >>= 1) { if (tid < off) red[tid] += red[tid + off]; __syncthreads(); }
  float mu = red[0] * (1.f / 128.f);
  __syncthreads();
  float d = z - mu;
  red[tid] = d * d; __syncthreads();
  for (int off = 64; off; off >>= 1) { if (tid < off) red[tid] += red[tid + off]; __syncthreads(); }
  float var = red[0] * (1.f / 128.f);
  float zn = d * rsqrtf(var + 1e-5f) * lng[tid] + lnb[tid];
  sz[tid] = fmaxf(zn, 0.f);
  __syncthreads();
  if (tid < 64) {
    float a = p2b[tid];
    for (int k = 0; k < 128; ++k) a += sz[k] * p2w[k * 64 + tid];
    s2[tid] = fmaxf(a, 0.f);
  }
  __syncthreads();
  if (tid < 64) {
    float p = s2[tid] * hw[tid];
    for (int off = 32; off; off >>= 1) p += __shfl_down(p, off, 64);
    if (tid == 0) out[b] = p + hb[0];
  }
}

extern "C" void kernel_launch(void* const* d_in, const int* in_sizes, int n_in,
                              void* d_out, int out_size, void* d_ws, size_t ws_size,
                              hipStream_t stream) {
  const float* x      = (const float*)d_in[0];
  const int*   ei     = (const int*)d_in[1];
  const float* ea     = (const float*)d_in[2];
  const int*   batch  = (const int*)d_in[3];
  const float* enc_w  = (const float*)d_in[4];
  const float* enc_b  = (const float*)d_in[5];
  const float* g1_wl  = (const float*)d_in[6];
  const float* g1_bl  = (const float*)d_in[7];
  const float* g1_wr  = (const float*)d_in[8];
  const float* g1_we  = (const float*)d_in[9];
  const float* g1_att = (const float*)d_in[10];
  const float* g1_b   = (const float*)d_in[11];
  const float* g2_wl  = (const float*)d_in[12];
  const float* g2_bl  = (const float*)d_in[13];
  const float* g2_wr  = (const float*)d_in[14];
  const float* g2_we  = (const float*)d_in[15];
  const float* g2_att = (const float*)d_in[16];
  const float* g2_b   = (const float*)d_in[17];
  const float* p1_w   = (const float*)d_in[18];
  const float* p1_b   = (const float*)d_in[19];
  const float* ln_g   = (const float*)d_in[20];
  const float* ln_b   = (const float*)d_in[21];
  const float* p2_w   = (const float*)d_in[22];
  const float* p2_b   = (const float*)d_in[23];
  const float* head_w = (const float*)d_in[24];
  const float* head_b = (const float*)d_in[25];
  float* out = (float*)d_out;

  char* ws = (char*)d_ws;
  size_t off = 0;
  auto alloc = [&](size_t bytes) -> void* {
    void* p = ws + off;
    off = (off + bytes + 255) & ~(size_t)255;
    return p;
  };
  unsigned short* xl   = (unsigned short*)alloc((size_t)NN * HC * 2);
  unsigned short* xr   = (unsigned short*)alloc((size_t)NN * HC * 2);
  unsigned short* h0   = (unsigned short*)alloc((size_t)NN * 64 * 2);
  unsigned short* hb16 = (unsigned short*)alloc((size_t)NN * HC * 2);
  unsigned short* wt1  = (unsigned short*)alloc((size_t)512 * 64 * 2);
  unsigned short* wt2  = (unsigned short*)alloc((size_t)512 * 256 * 2);
  float* pool      = (float*)alloc((size_t)GG * HC * 4);
  float* partial   = (float*)alloc((size_t)GATB * HC * 4);   // 12.8 MB
  int*   deg       = (int*)alloc((size_t)NN * 4);
  int*   rowstart  = (int*)alloc((size_t)(NN + 1) * 4);
  int*   cursor    = (int*)alloc((size_t)NN * 4);
  int*   bsum      = (int*)alloc((size_t)NB * 4);
  int2*  edges     = (int2*)alloc((size_t)NE * 8);
  int*   bounds    = (int*)alloc((size_t)(GG + 1) * 4);

  // encoder + weight prep + setup (zero deg/pool, seg bounds) in ONE launch
  head_kernel<<<ENCB + WCB + NB, 256, 0, stream>>>(
      x, enc_w, enc_b, h0, g1_wl, g1_wr, g2_wl, g2_wr, wt1, wt2,
      batch, deg, pool, bounds);

  // CSR build: degree -> blocksum -> rowstart(inline scan) -> fill
  degree_kernel<<<(NE + 255) / 256, 256, 0, stream>>>(ei, deg);
  blocksum_kernel<<<NB, 256, 0, stream>>>(deg, bsum);
  rowstart_kernel<<<NB, 256, 0, stream>>>(deg, bsum, rowstart, cursor);
  fill_kernel<<<(NE + 255) / 256, 256, 0, stream>>>(ei, ea, cursor, edges);

  const int MMB = ((NN + 127) / 128) * 4;   // 1564 matmul blocks

  // ---- GAT layer 1 (K=64): matmul -> xl/xr, then edge phase ----
  matmul_mfma_kernel<64><<<MMB, 256, 0, stream>>>(h0, wt1, g1_bl, xl, xr, NN);
  gat_fused_kernel<false><<<GATB, 256, 0, stream>>>(
      rowstart, edges, xl, xr, g1_we, g1_att, g1_b, hb16, batch, pool, nullptr);

  // ---- GAT layer 2 (K=256): matmul, then edge phase (pool fused, no atomics) ----
  matmul_mfma_kernel<256><<<MMB, 256, 0, stream>>>(hb16, wt2, g2_bl, xl, xr, NN);
  gat_fused_kernel<true><<<GATB, 256, 0, stream>>>(
      rowstart, edges, xl, xr, g2_we, g2_att, g2_b, nullptr, batch, pool, partial);

  // ---- parallel partial->pool reduction, then MLP head ----
  reduce_kernel<<<GG * 8, 256, 0, stream>>>(partial, bounds, pool);
  mlp_kernel<<<GG, 128, 0, stream>>>(pool, bounds, p1_w, p1_b, ln_g, ln_b,
                                     p2_w, p2_b, head_w, head_b, out);
}

// Round 12
// 304.746 us; speedup vs baseline: 1.0502x; 1.0502x over previous
//
#include <hip/hip_runtime.h>
#include <hip/hip_bf16.h>
#include <math.h>

#define NN 50000     // nodes
#define NE 400000    // edges
#define HH 4         // heads
#define CC 64        // per-head dim
#define HC 256       // H*C
#define GG 64        // graphs
#define NB 196       // scan blocks: ceil(NN/256)
#define ENCB 12500   // encoder blocks
#define WCB 640      // wconv blocks
#define GATB 12500   // gat blocks (4 nodes each)

typedef short v8s __attribute__((ext_vector_type(8)));
typedef float f32x4 __attribute__((ext_vector_type(4)));

static __device__ inline unsigned short f2bf(float v) {
  __hip_bfloat16 b = __float2bfloat16(v);
  return *reinterpret_cast<unsigned short*>(&b);
}
// packed bf16 pair -> f32 (bf16 value = bit pattern << 16)
static __device__ inline float bflo(unsigned u) { return __uint_as_float(u << 16); }
static __device__ inline float bfhi(unsigned u) { return __uint_as_float(u & 0xffff0000u); }

// width-16 xor-butterfly step via ds_swizzle BitMode: ONE DS instr, no VALU
// addr math. offset = (xor<<10)|0x1F.
static __device__ inline float swz_xor(float v, int imm) {
  switch (imm) {
    case 8: return __int_as_float(__builtin_amdgcn_ds_swizzle(__float_as_int(v), 0x201F));
    case 4: return __int_as_float(__builtin_amdgcn_ds_swizzle(__float_as_int(v), 0x101F));
    case 2: return __int_as_float(__builtin_amdgcn_ds_swizzle(__float_as_int(v), 0x081F));
    default: return __int_as_float(__builtin_amdgcn_ds_swizzle(__float_as_int(v), 0x041F));
  }
}

// async global->LDS, 16B per lane. LDS dest is wave-uniform base + lane*16.
static __device__ inline void gload_lds16(const void* g, void* l) {
  __builtin_amdgcn_global_load_lds(
      (const __attribute__((address_space(1))) void*)g,
      (__attribute__((address_space(3))) void*)l, 16, 0, 0);
}

// ---- head kernel: encoder + all 4 W preps + setup, region-dispatched ----
// bid <  ENCB               : encoder  h0 = relu(x @ enc_w + enc_b) -> bf16
// bid <  ENCB+WCB           : wconv    W[K,256] f32 -> Wt bf16 [256][K]
// bid <  ENCB+WCB+NB        : setup    zero deg, zero pool, seg bounds
__global__ __launch_bounds__(256) void head_kernel(
    const float* __restrict__ x, const float* __restrict__ enc_w,
    const float* __restrict__ enc_b, unsigned short* __restrict__ h0,
    const float* __restrict__ g1_wl, const float* __restrict__ g1_wr,
    const float* __restrict__ g2_wl, const float* __restrict__ g2_wr,
    unsigned short* __restrict__ wt1, unsigned short* __restrict__ wt2,
    const int* __restrict__ batch, int* __restrict__ deg,
    float* __restrict__ pool, int* __restrict__ bounds) {
  int bid = blockIdx.x, tid = threadIdx.x;
  if (bid < ENCB) {
    int idx = bid * 256 + tid;
    int node = idx >> 6, col = idx & 63;
    const float* xr = x + node * 8;
    float acc = enc_b[col];
#pragma unroll
    for (int k = 0; k < 8; ++k) acc += xr[k] * enc_w[k * 64 + col];
    h0[idx] = f2bf(fmaxf(acc, 0.f));
  } else if (bid < ENCB + WCB) {
    int idx = (bid - ENCB) * 256 + tid;
    const float* W; unsigned short* Wt; int K; int base;
    if (idx < 16384)        { W = g1_wl; Wt = wt1;                     K = 64;  base = idx; }
    else if (idx < 32768)   { W = g1_wr; Wt = wt1 + (size_t)256 * 64;  K = 64;  base = idx - 16384; }
    else if (idx < 98304)   { W = g2_wl; Wt = wt2;                     K = 256; base = idx - 32768; }
    else if (idx < 163840)  { W = g2_wr; Wt = wt2 + (size_t)256 * 256; K = 256; base = idx - 98304; }
    else return;
    int k = base >> 8, n = base & 255;
    Wt[n * K + k] = f2bf(W[base]);
  } else {
    int sb = bid - ENCB - WCB;           // 0..NB-1
    int i = sb * 256 + tid;
    if (i < NN) deg[i] = 0;
    if (sb < GG) pool[sb * 256 + tid] = 0.f;
    if (sb == NB - 1 && tid <= GG) {
      int g = tid, lo = 0, hi = NN;
      while (lo < hi) {
        int mid = (lo + hi) >> 1;
        if (batch[mid] < g) lo = mid + 1; else hi = mid;
      }
      bounds[g] = lo;
    }
  }
}

// ------- MFMA matmul: {xl,xr}(bf16)[M,256] = A(bf16) @ [Wl;Wr] (bias on xl) -------
// 2-phase double-buffered pipeline (T3-minimum), global_load_lds w16, swizzled.
template <int K>
__global__ __launch_bounds__(256) void matmul_mfma_kernel(
    const unsigned short* __restrict__ A, const unsigned short* __restrict__ Wt,
    const float* __restrict__ bias,
    unsigned short* __restrict__ outL, unsigned short* __restrict__ outR, int M) {
  const int mmb = ((M + 127) >> 7) << 2;
  int bid = blockIdx.x;
  {
    int q = mmb >> 3, r = mmb & 7;
    int xcd = bid & 7, off2 = bid >> 3;
    bid = (xcd < r ? xcd * (q + 1) : r * (q + 1) + (xcd - r) * q) + off2;
  }
  __shared__ __attribute__((aligned(16))) unsigned short lds[16384];
  const int tid = threadIdx.x;
  const int wave = tid >> 6;
  const int lane = tid & 63;
  const int quad = lane >> 4;
  const int lrow = lane & 15;
  const int wr = (wave & 1) * 64;
  const int wc = (wave >> 1) * 64;
  const int r0 = (bid >> 2) * 128;
  const int n0 = (bid & 3) * 128;

  f32x4 acc[4][4];
#pragma unroll
  for (int i = 0; i < 4; ++i)
#pragma unroll
    for (int j = 0; j < 4; ++j) acc[i][j] = (f32x4){0.f, 0.f, 0.f, 0.f};

  const int lrA0 = (wave * 2) * 16 + (lane >> 2);
  const int lrA1 = lrA0 + 16;
  const int c    = lane & 3;
  const int cs0  = c ^ ((lrA0 >> 1) & 3);
  const int cs1  = c ^ ((lrA1 >> 1) & 3);
  int ga0 = r0 + lrA0; if (ga0 >= M) ga0 = M - 1;
  int ga1 = r0 + lrA1; if (ga1 >= M) ga1 = M - 1;
  const unsigned short* srcA0 = A  + (size_t)ga0 * K + cs0 * 8;
  const unsigned short* srcA1 = A  + (size_t)ga1 * K + cs1 * 8;
  const unsigned short* srcB0 = Wt + (size_t)(n0 + lrA0) * K + cs0 * 8;
  const unsigned short* srcB1 = Wt + (size_t)(n0 + lrA1) * K + cs1 * 8;
  const int doff0 = (wave * 2 + 0) * 512;
  const int doff1 = (wave * 2 + 1) * 512;
  const int qsw = (quad ^ ((lrow >> 1) & 3)) * 8;

  constexpr int NT = K / 32;
  gload_lds16(srcA0, &lds[doff0]);
  gload_lds16(srcA1, &lds[doff1]);
  gload_lds16(srcB0, &lds[4096 + doff0]);
  gload_lds16(srcB1, &lds[4096 + doff1]);
  __syncthreads();

  int cur = 0;
#pragma unroll
  for (int t = 0; t < NT; ++t) {
    if (t + 1 < NT) {
      const int k0 = (t + 1) * 32;
      const int nb = (cur ^ 1) * 8192;
      gload_lds16(srcA0 + k0, &lds[nb + doff0]);
      gload_lds16(srcA1 + k0, &lds[nb + doff1]);
      gload_lds16(srcB0 + k0, &lds[nb + 4096 + doff0]);
      gload_lds16(srcB1 + k0, &lds[nb + 4096 + doff1]);
    }
    const unsigned short* base = &lds[cur * 8192];
    v8s af[4], bf[4];
#pragma unroll
    for (int rt = 0; rt < 4; ++rt)
      af[rt] = *(const v8s*)&base[(wr + rt * 16 + lrow) * 32 + qsw];
#pragma unroll
    for (int ct = 0; ct < 4; ++ct)
      bf[ct] = *(const v8s*)&base[4096 + (wc + ct * 16 + lrow) * 32 + qsw];
#pragma unroll
    for (int rt = 0; rt < 4; ++rt)
#pragma unroll
      for (int ct = 0; ct < 4; ++ct)
        acc[rt][ct] = __builtin_amdgcn_mfma_f32_16x16x32_bf16(af[rt], bf[ct], acc[rt][ct], 0, 0, 0);
    __syncthreads();
    cur ^= 1;
  }

  const bool isL = (n0 < 256);
  unsigned short* outp = isL ? outL : outR;
  const int cbase = isL ? n0 : (n0 - 256);
  constexpr int SP = 136;
  unsigned short* stage = lds;

#pragma unroll
  for (int rt = 0; rt < 4; ++rt) {
    __syncthreads();
#pragma unroll
    for (int ct = 0; ct < 4; ++ct) {
      int col = wc + ct * 16 + lrow;
      float b = isL ? bias[cbase + col] : 0.f;
#pragma unroll
      for (int r = 0; r < 4; ++r) {
        int sr = (wave & 1) * 16 + quad * 4 + r;
        stage[sr * SP + col] = f2bf(acc[rt][ct][r] + b);
      }
    }
    __syncthreads();
    int sr = tid >> 3;
    int c0 = (tid & 7) * 16;
    int grow = r0 + (sr >> 4) * 64 + rt * 16 + (sr & 15);
    if (grow < M) {
      uint4 v0 = *(const uint4*)&stage[sr * SP + c0];
      uint4 v1 = *(const uint4*)&stage[sr * SP + c0 + 8];
      *(uint4*)&outp[(size_t)grow * 256 + cbase + c0] = v0;
      *(uint4*)&outp[(size_t)grow * 256 + cbase + c0 + 8] = v1;
    }
  }
}

// ---------------- CSR build ----------------
__global__ void degree_kernel(const int* __restrict__ ei, int* __restrict__ deg) {
  int e = blockIdx.x * 256 + threadIdx.x;
  if (e < NE) atomicAdd(&deg[ei[NE + e]], 1);
}

__global__ __launch_bounds__(256) void blocksum_kernel(
    const int* __restrict__ deg, int* __restrict__ bsum) {
  int t = threadIdx.x;
  int i = blockIdx.x * 256 + t;
  int v = (i < NN) ? deg[i] : 0;
#pragma unroll
  for (int off = 32; off; off >>= 1) v += __shfl_down(v, off, 64);
  __shared__ int ws[4];
  if ((t & 63) == 0) ws[t >> 6] = v;
  __syncthreads();
  if (t == 0) bsum[blockIdx.x] = ws[0] + ws[1] + ws[2] + ws[3];
}

// rowstart with INLINE block-prefix: each block reduces bsum[0..b) itself
// (196 coalesced ints + wave reduce) -- deletes the serial single-block
// blockscan launch. No cross-block waits. (r11: neutral-to-positive, kept)
__global__ __launch_bounds__(256) void rowstart_kernel(
    const int* __restrict__ deg, const int* __restrict__ bsum,
    int* __restrict__ rowstart, int* __restrict__ cursor) {
  __shared__ int s[256];
  __shared__ int ws[4];
  __shared__ int wt[4];
  int t = threadIdx.x;
  int b = blockIdx.x;
  int bv = (t < NB) ? bsum[t] : 0;
  int cpre = (t < b) ? bv : 0;
#pragma unroll
  for (int off = 32; off; off >>= 1) cpre += __shfl_down(cpre, off, 64);
  if ((t & 63) == 0) ws[t >> 6] = cpre;
  int tot = bv;
#pragma unroll
  for (int off = 32; off; off >>= 1) tot += __shfl_down(tot, off, 64);
  if ((t & 63) == 0) wt[t >> 6] = tot;
  __syncthreads();
  int pre = ws[0] + ws[1] + ws[2] + ws[3];
  int i = b * 256 + t;
  int v = (i < NN) ? deg[i] : 0;
  s[t] = v;
  __syncthreads();
  for (int off = 1; off < 256; off <<= 1) {
    int x = s[t];
    int y = (t >= off) ? s[t - off] : 0;
    __syncthreads();
    s[t] = x + y;
    __syncthreads();
  }
  if (i < NN) {
    int rs = pre + s[t] - v;
    rowstart[i] = rs;
    cursor[i] = rs;
  }
  if (b == NB - 1 && t == 0)
    rowstart[NN] = wt[0] + wt[1] + wt[2] + wt[3];
}

// CSR fill: int2 (src BYTE OFFSET = src*512, ea-bits) -> one aligned 8B store.
__global__ void fill_kernel(const int* __restrict__ ei, const float* __restrict__ ea,
                            int* __restrict__ cursor, int2* __restrict__ edges) {
  int e = blockIdx.x * 256 + threadIdx.x;
  if (e < NE) {
    int d = ei[NE + e];
    int pos = atomicAdd(&cursor[d], 1);
    edges[pos] = make_int2(ei[e] << 9, __float_as_int(ea[e]));
  }
}

// ---------------- fused GATv2 edge phase: wave per dst node ----
// r9/r10-measured body (45.2us): 4-deep rotation pipeline, VGPR=32, ~8
// waves/SIMD. (r11's deeper 2-stage pipeline cost VGPR 32->40 -> occupancy
// 59->44% -> +9us; TLP latency-hiding beats rotation-move savings here.)
// POOL=true (layer 2): LDS-stage output, last-arriving wave emits ONE plain
// 1KB store to partial[blockIdx]; straddlers (~63/12500) use atomics to pool.
template <bool POOL>
__global__ __launch_bounds__(256) void gat_fused_kernel(
    const int* __restrict__ rowstart, const int2* __restrict__ edges,
    const unsigned short* __restrict__ xl, const unsigned short* __restrict__ xr,
    const float* __restrict__ we, const float* __restrict__ att,
    const float* __restrict__ bias, unsigned short* __restrict__ outb,
    const int* __restrict__ batch, float* __restrict__ pool,
    float* __restrict__ partial) {
  __shared__ float pacc[POOL ? 4 : 1][POOL ? 256 : 1];
  __shared__ int pb[4];
  __shared__ int done;
  int tid = threadIdx.x;
  int node = (blockIdx.x * 256 + tid) >> 6;
  int lane = tid & 63;
  int wave = tid >> 6;
  if constexpr (POOL) {
    if (tid == 0) done = 0;
    if (lane == 0) pb[wave] = batch[node];
    __syncthreads();                     // uniform start point: ~free; orders done=0
  }
  int r0 = __builtin_amdgcn_readfirstlane(rowstart[node]);
  int r1 = __builtin_amdgcn_readfirstlane(rowstart[node + 1]);
  const char* xlb = (const char*)xl;          // UNIFORM gather base
  const unsigned lane8 = (unsigned)lane * 8u;
  uint2 rp = ((const uint2*)xr)[(size_t)node * 64 + lane];
  float4 r = make_float4(bflo(rp.x), bfhi(rp.x), bflo(rp.y), bfhi(rp.y));
  float4 wv = ((const float4*)we)[lane];
  float4 at = ((const float4*)att)[lane];
  const float LOG2E = 1.442695040888963f;
  at.x *= LOG2E; at.y *= LOG2E; at.z *= LOG2E; at.w *= LOG2E;
  float4 acc = make_float4(0.f, 0.f, 0.f, 0.f);
  float denom = 0.f;

  auto edge_step = [&](float eav, uint2 p) {
    float4 a = make_float4(bflo(p.x), bfhi(p.x), bflo(p.y), bfhi(p.y));
    float s0 = a.x + (r.x + eav * wv.x);
    float s1 = a.y + (r.y + eav * wv.y);
    float s2 = a.z + (r.z + eav * wv.z);
    float s3 = a.w + (r.w + eav * wv.w);
    s0 = fmaxf(s0, 0.2f * s0);
    s1 = fmaxf(s1, 0.2f * s1);
    s2 = fmaxf(s2, 0.2f * s2);
    s3 = fmaxf(s3, 0.2f * s3);
    float p4 = (s0 * at.x + s1 * at.y) + (s2 * at.z + s3 * at.w);
    p4 += swz_xor(p4, 8);
    p4 += swz_xor(p4, 4);
    p4 += swz_xor(p4, 2);
    p4 += swz_xor(p4, 1);
    float ex = exp2f(p4);
    denom += ex;
    acc.x += ex * a.x; acc.y += ex * a.y; acc.z += ex * a.z; acc.w += ex * a.w;
  };
  auto gath = [&](int byteoff) {
    return *(const uint2*)(xlb + (unsigned)byteoff + lane8);
  };

  int i = r0;
  if (i + 8 <= r1) {                      // 4-deep pipeline + prefetch rotation
    int2 e0 = edges[i];     int2 e1 = edges[i + 1];
    int2 e2 = edges[i + 2]; int2 e3 = edges[i + 3];
    uint2 p0 = gath(e0.x), p1 = gath(e1.x), p2 = gath(e2.x), p3 = gath(e3.x);
    for (; i + 8 <= r1; i += 4) {
      int2 f0 = edges[i + 4]; int2 f1 = edges[i + 5];
      int2 f2 = edges[i + 6]; int2 f3 = edges[i + 7];
      uint2 q0 = gath(f0.x), q1 = gath(f1.x), q2 = gath(f2.x), q3 = gath(f3.x);
      edge_step(__int_as_float(e0.y), p0);
      edge_step(__int_as_float(e1.y), p1);
      edge_step(__int_as_float(e2.y), p2);
      edge_step(__int_as_float(e3.y), p3);
      e0 = f0; e1 = f1; e2 = f2; e3 = f3;
      p0 = q0; p1 = q1; p2 = q2; p3 = q3;
    }
    edge_step(__int_as_float(e0.y), p0);
    edge_step(__int_as_float(e1.y), p1);
    edge_step(__int_as_float(e2.y), p2);
    edge_step(__int_as_float(e3.y), p3);
    i += 4;
  } else if (i + 4 <= r1) {
    int2 e0 = edges[i];     int2 e1 = edges[i + 1];
    int2 e2 = edges[i + 2]; int2 e3 = edges[i + 3];
    uint2 p0 = gath(e0.x), p1 = gath(e1.x), p2 = gath(e2.x), p3 = gath(e3.x);
    edge_step(__int_as_float(e0.y), p0);
    edge_step(__int_as_float(e1.y), p1);
    edge_step(__int_as_float(e2.y), p2);
    edge_step(__int_as_float(e3.y), p3);
    i += 4;
  }
  for (; i < r1; ++i) {
    int2 e = edges[i];
    edge_step(__int_as_float(e.y), gath(e.x));
  }

  float inv = 1.f / (denom + 1e-16f);
  float4 bv = ((const float4*)bias)[lane];
  float4 o;
  o.x = fmaxf(acc.x * inv + bv.x, 0.f);
  o.y = fmaxf(acc.y * inv + bv.y, 0.f);
  o.z = fmaxf(acc.z * inv + bv.z, 0.f);
  o.w = fmaxf(acc.w * inv + bv.w, 0.f);
  uint2 pk;
  pk.x = (unsigned)f2bf(o.x) | ((unsigned)f2bf(o.y) << 16);
  pk.y = (unsigned)f2bf(o.z) | ((unsigned)f2bf(o.w) << 16);
  if constexpr (!POOL) {
    ((uint2*)outb)[(size_t)node * 64 + lane] = pk;
  } else {
    // bf16-rounded f32 values (bitwise = pool_kernel's summands)
    *(float4*)&pacc[wave][lane * 4] =
        make_float4(bflo(pk.x), bfhi(pk.x), bflo(pk.y), bfhi(pk.y));
    __threadfence_block();               // drain ds_writes before the bump
    int prev = 0;
    if (lane == 0) prev = atomicAdd(&done, 1);
    prev = __shfl(prev, 0, 64);
    if (prev == 3) {                     // last wave flushes; others exit now
      int b0 = pb[0], b1 = pb[1], b2 = pb[2], b3 = pb[3];
      float* pp = partial + (size_t)blockIdx.x * 256;
      if (b0 == b3 && b0 == b1 && b1 == b2) {   // sorted batch: common case
#pragma unroll
        for (int k = 0; k < 4; ++k) {
          int ch = lane + 64 * k;        // coalesced channel walk
          float s = (pacc[0][ch] + pacc[1][ch]) + (pacc[2][ch] + pacc[3][ch]);
          pp[ch] = s;                    // plain store, no atomic
        }
      } else {                           // straddler: zero partial + atomics
#pragma unroll
        for (int k = 0; k < 4; ++k) {
          int ch = lane + 64 * k;
          pp[ch] = 0.f;
          atomicAdd(&pool[b0 * 256 + ch], pacc[0][ch]);
          atomicAdd(&pool[b1 * 256 + ch], pacc[1][ch]);
          atomicAdd(&pool[b2 * 256 + ch], pacc[2][ch]);
          atomicAdd(&pool[b3 * 256 + ch], pacc[3][ch]);
        }
      }
    }
  }
}

// ---------------- partial -> pool reduction: graph x 8 segments ----------------
// 512 blocks x 256 thr (thread = channel): each block sums ~25 partial rows
// (coalesced 1KB reads) and issues ONE atomicAdd per channel.
__global__ __launch_bounds__(256) void reduce_kernel(
    const float* __restrict__ partial, const int* __restrict__ bounds,
    float* __restrict__ pool) {
  int g = blockIdx.x >> 3;
  int seg = blockIdx.x & 7;
  int ch = threadIdx.x;
  int lo = bounds[g], hi = bounds[g + 1];
  int pb0 = lo >> 2, pb1 = (hi + 3) >> 2;
  int per = (pb1 - pb0 + 7) >> 3;
  int s0 = pb0 + seg * per;
  int s1 = s0 + per; if (s1 > pb1) s1 = pb1;
  float s = 0.f;
#pragma unroll 4
  for (int p = s0; p < s1; ++p) s += partial[(size_t)p * 256 + ch];
  if (s0 < s1) atomicAdd(&pool[g * 256 + ch], s);
}

// ---------------- final MLP: one block (128 thr) per graph ----------------
__global__ __launch_bounds__(128) void mlp_kernel(
    const float* __restrict__ pool, const int* __restrict__ bounds,
    const float* __restrict__ p1w, const float* __restrict__ p1b,
    const float* __restrict__ lng, const float* __restrict__ lnb,
    const float* __restrict__ p2w, const float* __restrict__ p2b,
    const float* __restrict__ hw, const float* __restrict__ hb,
    float* __restrict__ out) {
  __shared__ float sg[256];
  __shared__ float red[128];
  __shared__ float sz[128];
  __shared__ float s2[64];
  int b = blockIdx.x, tid = threadIdx.x;
  float cntf = (float)(bounds[b + 1] - bounds[b]);
  float invc = 1.f / fmaxf(cntf, 1.f);
  for (int i = tid; i < 256; i += 128) sg[i] = pool[b * 256 + i] * invc;
  __syncthreads();
  float z = p1b[tid];
  for (int k = 0; k < 256; ++k) z += sg[k] * p1w[k * 128 + tid];
  red[tid] = z; __syncthreads();
  for (int off = 64; off; off >>= 1) { if (tid < off) red[tid] += red[tid + off]; __syncthreads(); }
  float mu = red[0] * (1.f / 128.f);
  __syncthreads();
  float d = z - mu;
  red[tid] = d * d; __syncthreads();
  for (int off = 64; off; off >>= 1) { if (tid < off) red[tid] += red[tid + off]; __syncthreads(); }
  float var = red[0] * (1.f / 128.f);
  float zn = d * rsqrtf(var + 1e-5f) * lng[tid] + lnb[tid];
  sz[tid] = fmaxf(zn, 0.f);
  __syncthreads();
  if (tid < 64) {
    float a = p2b[tid];
    for (int k = 0; k < 128; ++k) a += sz[k] * p2w[k * 64 + tid];
    s2[tid] = fmaxf(a, 0.f);
  }
  __syncthreads();
  if (tid < 64) {
    float p = s2[tid] * hw[tid];
    for (int off = 32; off; off >>= 1) p += __shfl_down(p, off, 64);
    if (tid == 0) out[b] = p + hb[0];
  }
}

extern "C" void kernel_launch(void* const* d_in, const int* in_sizes, int n_in,
                              void* d_out, int out_size, void* d_ws, size_t ws_size,
                              hipStream_t stream) {
  const float* x      = (const float*)d_in[0];
  const int*   ei     = (const int*)d_in[1];
  const float* ea     = (const float*)d_in[2];
  const int*   batch  = (const int*)d_in[3];
  const float* enc_w  = (const float*)d_in[4];
  const float* enc_b  = (const float*)d_in[5];
  const float* g1_wl  = (const float*)d_in[6];
  const float* g1_bl  = (const float*)d_in[7];
  const float* g1_wr  = (const float*)d_in[8];
  const float* g1_we  = (const float*)d_in[9];
  const float* g1_att = (const float*)d_in[10];
  const float* g1_b   = (const float*)d_in[11];
  const float* g2_wl  = (const float*)d_in[12];
  const float* g2_bl  = (const float*)d_in[13];
  const float* g2_wr  = (const float*)d_in[14];
  const float* g2_we  = (const float*)d_in[15];
  const float* g2_att = (const float*)d_in[16];
  const float* g2_b   = (const float*)d_in[17];
  const float* p1_w   = (const float*)d_in[18];
  const float* p1_b   = (const float*)d_in[19];
  const float* ln_g   = (const float*)d_in[20];
  const float* ln_b   = (const float*)d_in[21];
  const float* p2_w   = (const float*)d_in[22];
  const float* p2_b   = (const float*)d_in[23];
  const float* head_w = (const float*)d_in[24];
  const float* head_b = (const float*)d_in[25];
  float* out = (float*)d_out;

  char* ws = (char*)d_ws;
  size_t off = 0;
  auto alloc = [&](size_t bytes) -> void* {
    void* p = ws + off;
    off = (off + bytes + 255) & ~(size_t)255;
    return p;
  };
  unsigned short* xl   = (unsigned short*)alloc((size_t)NN * HC * 2);
  unsigned short* xr   = (unsigned short*)alloc((size_t)NN * HC * 2);
  unsigned short* h0   = (unsigned short*)alloc((size_t)NN * 64 * 2);
  unsigned short* hb16 = (unsigned short*)alloc((size_t)NN * HC * 2);
  unsigned short* wt1  = (unsigned short*)alloc((size_t)512 * 64 * 2);
  unsigned short* wt2  = (unsigned short*)alloc((size_t)512 * 256 * 2);
  float* pool      = (float*)alloc((size_t)GG * HC * 4);
  float* partial   = (float*)alloc((size_t)GATB * HC * 4);   // 12.8 MB
  int*   deg       = (int*)alloc((size_t)NN * 4);
  int*   rowstart  = (int*)alloc((size_t)(NN + 1) * 4);
  int*   cursor    = (int*)alloc((size_t)NN * 4);
  int*   bsum      = (int*)alloc((size_t)NB * 4);
  int2*  edges     = (int2*)alloc((size_t)NE * 8);
  int*   bounds    = (int*)alloc((size_t)(GG + 1) * 4);

  // encoder + weight prep + setup (zero deg/pool, seg bounds) in ONE launch
  head_kernel<<<ENCB + WCB + NB, 256, 0, stream>>>(
      x, enc_w, enc_b, h0, g1_wl, g1_wr, g2_wl, g2_wr, wt1, wt2,
      batch, deg, pool, bounds);

  // CSR build: degree -> blocksum -> rowstart(inline scan) -> fill
  degree_kernel<<<(NE + 255) / 256, 256, 0, stream>>>(ei, deg);
  blocksum_kernel<<<NB, 256, 0, stream>>>(deg, bsum);
  rowstart_kernel<<<NB, 256, 0, stream>>>(deg, bsum, rowstart, cursor);
  fill_kernel<<<(NE + 255) / 256, 256, 0, stream>>>(ei, ea, cursor, edges);

  const int MMB = ((NN + 127) / 128) * 4;   // 1564 matmul blocks

  // ---- GAT layer 1 (K=64): matmul -> xl/xr, then edge phase ----
  matmul_mfma_kernel<64><<<MMB, 256, 0, stream>>>(h0, wt1, g1_bl, xl, xr, NN);
  gat_fused_kernel<false><<<GATB, 256, 0, stream>>>(
      rowstart, edges, xl, xr, g1_we, g1_att, g1_b, hb16, batch, pool, nullptr);

  // ---- GAT layer 2 (K=256): matmul, then edge phase (pool fused, no atomics) ----
  matmul_mfma_kernel<256><<<MMB, 256, 0, stream>>>(hb16, wt2, g2_bl, xl, xr, NN);
  gat_fused_kernel<true><<<GATB, 256, 0, stream>>>(
      rowstart, edges, xl, xr, g2_we, g2_att, g2_b, nullptr, batch, pool, partial);

  // ---- parallel partial->pool reduction, then MLP head ----
  reduce_kernel<<<GG * 8, 256, 0, stream>>>(partial, bounds, pool);
  mlp_kernel<<<GG, 128, 0, stream>>>(pool, bounds, p1_w, p1_b, ln_g, ln_b,
                                     p2_w, p2_b, head_w, head_b, out);
}